// Round 5
// baseline (562.792 us; speedup 1.0000x reference)
//
#include <hip/hip_runtime.h>
#include <hip/hip_bf16.h>
#include <math.h>

constexpr int F  = 256;
constexpr int ED = 32;
constexpr int H  = 128;

typedef __attribute__((ext_vector_type(8))) short    short8v;
typedef __attribute__((ext_vector_type(4))) float    float4v;
typedef __attribute__((ext_vector_type(8))) _Float16 half8v;

static __device__ __forceinline__ unsigned short f2bf(float f) {
    unsigned int u = __float_as_uint(f);
    unsigned int r = (u + 0x7FFFu + ((u >> 16) & 1u)) >> 16;   // RNE
    return (unsigned short)r;
}

// bijective XCD swizzle (m204): consecutive WORK chunks land on the SAME XCD
static __device__ __forceinline__ int xcd_chunk(int bid, int nwg) {
    int q = nwg >> 3, r = nwg & 7;
    int xcd = bid & 7, idx = bid >> 3;
    return (xcd < r ? xcd * (q + 1) : r * (q + 1) + (xcd - r) * q) + idx;
}

// ---------------- P0: pack weights into MFMA B-fragment order ----------------
__global__ __launch_bounds__(256) void pack_kernel(
    const float* __restrict__ we_src, const float* __restrict__ we_dst,
    const float* __restrict__ wc, unsigned short* __restrict__ Wp)
{
    int id = blockIdx.x * 256 + threadIdx.x;
    if (id >= 12 * 8 * 64) return;
    int lane = id & 63;
    int ks   = (id >> 6) & 7;
    int tile = id >> 9;
    int col  = tile * 16 + (lane & 15);
    int kb   = ks * 32 + (lane >> 4) * 8;

    short8v v;
    #pragma unroll
    for (int j = 0; j < 8; ++j) {
        int k = kb + j;
        float w;
        if (col < 32)       w = we_src[k * ED + col];
        else if (col < 64)  w = we_dst[k * ED + (col - 32)];
        else                w = wc[k * H + (col - 64)];
        v[j] = (short)f2bf(w);
    }
    *(short8v*)(Wp + (size_t)id * 8) = v;
}

// ---------------- P1: MFMA GEMM -> psh/pdh/hh (f16) ----------------
__global__ __launch_bounds__(256) void gemm_kernel(
    const float* __restrict__ x, const unsigned short* __restrict__ Wp,
    const float* __restrict__ bc,
    _Float16* __restrict__ psh, _Float16* __restrict__ pdh,
    _Float16* __restrict__ hh, int M16)
{
    __shared__ __align__(16) unsigned char As[16 * 512];

    const int t    = threadIdx.x;
    const int w    = t >> 6;
    const int lane = t & 63;

    const short8v* WpV = (const short8v*)Wp;
    short8v Bfr[3][8];
    #pragma unroll
    for (int ct = 0; ct < 3; ++ct)
        #pragma unroll
        for (int ks = 0; ks < 8; ++ks)
            Bfr[ct][ks] = WpV[(((w * 3 + ct) * 8 + ks) << 6) + lane];

    const int srow = t >> 4;
    const int sseg = t & 15;
    const int ssw  = (srow & 7) << 4;

    const int arow = lane & 15;
    const int asw  = (arow & 7) << 4;
    const int akb  = (lane >> 4) * 16;

    const int crow0 = (lane >> 4) * 4;
    const int ccol  = lane & 15;

    for (int rt = blockIdx.x; rt < M16; rt += gridDim.x) {
        const int n0 = rt * 16;
        {
            const float4* src = (const float4*)(x + (size_t)(n0 + srow) * F + sseg * 16);
            float4 f0 = src[0], f1 = src[1], f2 = src[2], f3 = src[3];
            short8v lo, hi;
            lo[0] = (short)f2bf(f0.x); lo[1] = (short)f2bf(f0.y);
            lo[2] = (short)f2bf(f0.z); lo[3] = (short)f2bf(f0.w);
            lo[4] = (short)f2bf(f1.x); lo[5] = (short)f2bf(f1.y);
            lo[6] = (short)f2bf(f1.z); lo[7] = (short)f2bf(f1.w);
            hi[0] = (short)f2bf(f2.x); hi[1] = (short)f2bf(f2.y);
            hi[2] = (short)f2bf(f2.z); hi[3] = (short)f2bf(f2.w);
            hi[4] = (short)f2bf(f3.x); hi[5] = (short)f2bf(f3.y);
            hi[6] = (short)f2bf(f3.z); hi[7] = (short)f2bf(f3.w);
            *(short8v*)&As[srow * 512 + ((sseg * 32 +  0) ^ ssw)] = lo;
            *(short8v*)&As[srow * 512 + ((sseg * 32 + 16) ^ ssw)] = hi;
        }
        __syncthreads();

        float4v accs[3];
        #pragma unroll
        for (int ct = 0; ct < 3; ++ct) accs[ct] = (float4v){0.f, 0.f, 0.f, 0.f};

        #pragma unroll
        for (int ks = 0; ks < 8; ++ks) {
            short8v a = *(const short8v*)&As[arow * 512 + ((ks * 64 + akb) ^ asw)];
            accs[0] = __builtin_amdgcn_mfma_f32_16x16x32_bf16(a, Bfr[0][ks], accs[0], 0, 0, 0);
            accs[1] = __builtin_amdgcn_mfma_f32_16x16x32_bf16(a, Bfr[1][ks], accs[1], 0, 0, 0);
            accs[2] = __builtin_amdgcn_mfma_f32_16x16x32_bf16(a, Bfr[2][ks], accs[2], 0, 0, 0);
        }

        #pragma unroll
        for (int ct = 0; ct < 3; ++ct) {
            const int gcol = w * 48 + ct * 16 + ccol;
            #pragma unroll
            for (int r = 0; r < 4; ++r) {
                const int row = n0 + crow0 + r;
                float v = accs[ct][r];
                if (gcol < 32) {
                    psh[(size_t)row * ED + gcol] = (_Float16)v;
                } else if (gcol < 64) {
                    pdh[(size_t)row * ED + (gcol - 32)] = (_Float16)v;
                } else {
                    float b = bc[gcol - 64];
                    hh[(size_t)row * H + (gcol - 64)] = (_Float16)fmaxf(v + b, 0.f);
                }
            }
        }
        __syncthreads();
    }
}

// ---------------- S1: histogram of dst buckets ----------------
__global__ __launch_bounds__(256) void hist_kernel(
    const int* __restrict__ ei, int* __restrict__ hist, int E)
{
    int e = blockIdx.x * 256 + threadIdx.x;
    if (e < E) atomicAdd(&hist[ei[E + e] >> 4], 1);
}

// ---------------- S2: exclusive scan (K <= 4096), writes cursor ----------------
__global__ __launch_bounds__(1024) void scan_kernel(
    const int* __restrict__ hist, int* __restrict__ cursor, int K)
{
    __shared__ int s[4096];
    __shared__ int part[1024];
    const int t = threadIdx.x;
    for (int i = t; i < 4096; i += 1024) s[i] = (i < K) ? hist[i] : 0;
    __syncthreads();
    int a0 = s[4*t], a1 = s[4*t+1], a2 = s[4*t+2], a3 = s[4*t+3];
    int l1 = a0 + a1, l2 = l1 + a2, l3 = l2 + a3;
    part[t] = l3;
    __syncthreads();
    for (int d = 1; d < 1024; d <<= 1) {
        int v = (t >= d) ? part[t - d] : 0;
        __syncthreads();
        part[t] += v;
        __syncthreads();
    }
    int off = (t > 0) ? part[t - 1] : 0;
    if (4*t   < K) cursor[4*t]   = off;
    if (4*t+1 < K) cursor[4*t+1] = off + a0;
    if (4*t+2 < K) cursor[4*t+2] = off + l1;
    if (4*t+3 < K) cursor[4*t+3] = off + l2;
}

// ---------------- S3: scatter edges into dst-bucket order ----------------
__global__ __launch_bounds__(256) void scatter_kernel(
    const int* __restrict__ ei, int* __restrict__ cursor,
    int2* __restrict__ sd, int E)
{
    int e = blockIdx.x * 256 + threadIdx.x;
    if (e >= E) return;
    int s = ei[e], d = ei[E + e];
    int pos = atomicAdd(&cursor[d >> 4], 1);
    sd[pos] = make_int2(s, d);
}

// ---------------- B: edge gate + deg (sorted edges, XCD-chunked) ----------------
__global__ __launch_bounds__(256) void edge_gate_kernel(
    const int2* __restrict__ sd, const _Float16* __restrict__ psh,
    const _Float16* __restrict__ pdh, const float* __restrict__ be,
    const float* __restrict__ we2, const float* __restrict__ be2,
    float* __restrict__ gate, float* __restrict__ deg, int E)
{
    __shared__ float sbe[ED], swe2[ED];
    const int t = threadIdx.x;
    if (t < ED) { sbe[t] = be[t]; swe2[t] = we2[t]; }
    __syncthreads();

    const int wg = xcd_chunk(blockIdx.x, gridDim.x);
    const int e = wg * 64 + (t >> 2);
    if (e >= E) return;
    const int seg = t & 3;
    const int2 p = sd[e];

    half8v a = *(const half8v*)(psh + (size_t)p.x * ED + seg * 8);
    half8v b = *(const half8v*)(pdh + (size_t)p.y * ED + seg * 8);
    float part = 0.f;
    #pragma unroll
    for (int j = 0; j < 8; ++j) {
        int k = seg * 8 + j;
        part += fmaxf((float)a[j] + (float)b[j] + sbe[k], 0.f) * swe2[k];
    }
    part += __shfl_xor(part, 1);
    part += __shfl_xor(part, 2);

    if (seg == 0) {
        float logit = part + be2[0];
        float sg = 1.0f / (1.0f + expf(-logit));
        float gt = fminf(fmaxf(sg * 1.2f - 0.1f, 0.0f), 1.0f);
        gate[e] = gt;
        if (gt > 0.0f) atomicAdd(&deg[p.y], gt);
    }
}

// ---------------- C1: grid-wide max(deg) ----------------
__global__ __launch_bounds__(256) void stats_max_kernel(
    const float* __restrict__ deg, int* __restrict__ mmax, int N)
{
    float m = 0.0f;   // deg >= 0
    for (int i = blockIdx.x * 256 + threadIdx.x; i < N; i += gridDim.x * 256)
        m = fmaxf(m, deg[i]);
    #pragma unroll
    for (int k = 1; k < 64; k <<= 1) m = fmaxf(m, __shfl_xor(m, k));
    if ((threadIdx.x & 63) == 0)
        atomicMax(mmax, __float_as_int(m));
}

// ---------------- C2: grid-wide sum exp(deg - mx) ----------------
__global__ __launch_bounds__(256) void stats_sum_kernel(
    const float* __restrict__ deg, const int* __restrict__ mmax,
    float* __restrict__ S, int N)
{
    const float mx = __int_as_float(*mmax);
    float sum = 0.0f;
    for (int i = blockIdx.x * 256 + threadIdx.x; i < N; i += gridDim.x * 256)
        sum += expf(deg[i] - mx);
    #pragma unroll
    for (int k = 1; k < 64; k <<= 1) sum += __shfl_xor(sum, k);
    if ((threadIdx.x & 63) == 0) atomicAdd(S, sum);
}

// ---------------- D: att + c elementwise ----------------
__global__ __launch_bounds__(256) void attc_kernel(
    const float* __restrict__ deg, const int* __restrict__ mmax,
    const float* __restrict__ S,
    float* __restrict__ att, float* __restrict__ c, int N)
{
    const int i = blockIdx.x * 256 + threadIdx.x;
    if (i >= N) return;
    const float mx = __int_as_float(*mmax);
    float a = expf(deg[i] - mx) / S[0];
    att[i] = a;
    c[i] = a / (deg[i] + 1e-6f);
}

// ---------------- E: u[src] += gate*c[dst] (sorted stream, XCD-chunked) ------
__global__ __launch_bounds__(256) void edge_u_kernel(
    const int2* __restrict__ sd, const float* __restrict__ gate,
    const float* __restrict__ c, float* __restrict__ u, int E)
{
    const int wg = xcd_chunk(blockIdx.x, gridDim.x);
    const int e = wg * 256 + threadIdx.x;
    if (e >= E) return;
    float gt = gate[e];
    if (gt != 0.f) {
        int2 p = sd[e];
        atomicAdd(&u[p.x], gt * c[p.y]);
    }
}

// ---------------- F: g = sum_i (att[i]+u[i]) * h[i,:] ----------------
__global__ __launch_bounds__(128) void pool_kernel(
    const _Float16* __restrict__ hh, const float* __restrict__ att,
    const float* __restrict__ u, float* __restrict__ gacc, int N)
{
    const int t = threadIdx.x;
    float acc = 0.f;
    for (int n = blockIdx.x; n < N; n += gridDim.x) {
        float wgt = att[n] + u[n];
        acc += wgt * (float)hh[(size_t)n * H + t];
    }
    atomicAdd(&gacc[t], acc);
}

// ---------------- G: classifier (1 wave) ----------------
__global__ __launch_bounds__(64) void cls_kernel(
    const float* __restrict__ gacc, const float* __restrict__ w1,
    const float* __restrict__ b1, const float* __restrict__ ln_g,
    const float* __restrict__ ln_b, const float* __restrict__ w2,
    const float* __restrict__ b2, float* __restrict__ out)
{
    __shared__ float gs[H];
    const int t = threadIdx.x;
    gs[t] = gacc[t];
    gs[t + 64] = gacc[t + 64];
    __syncthreads();

    float acc = b1[t];
    #pragma unroll 4
    for (int k = 0; k < H; ++k) acc += gs[k] * w1[k * 64 + t];
    float z = fmaxf(acc, 0.f);

    float sm = z;
    #pragma unroll
    for (int m = 1; m < 64; m <<= 1) sm += __shfl_xor(sm, m);
    float mn = sm * (1.0f / 64.0f);
    float dv = (z - mn) * (z - mn);
    float sv = dv;
    #pragma unroll
    for (int m = 1; m < 64; m <<= 1) sv += __shfl_xor(sv, m);
    float var = sv * (1.0f / 64.0f);

    float zn = (z - mn) * rsqrtf(var + 1e-5f) * ln_g[t] + ln_b[t];

    float w20 = w2[t * 2 + 0];
    float w21 = w2[t * 2 + 1];
    float ga = w20 * w20, gb = w20 * w21, gc = w21 * w21;
    float p0 = zn * w20, p1 = zn * w21;
    #pragma unroll
    for (int m = 1; m < 64; m <<= 1) {
        ga += __shfl_xor(ga, m);
        gb += __shfl_xor(gb, m);
        gc += __shfl_xor(gc, m);
        p0 += __shfl_xor(p0, m);
        p1 += __shfl_xor(p1, m);
    }
    if (t == 0) {
        float tr = ga + gc;
        float df = ga - gc;
        float eig = 0.5f * (tr + sqrtf(df * df + 4.0f * gb * gb));
        float sigma = sqrtf(eig);
        out[0] = p0 / sigma + b2[0];
        out[1] = p1 / sigma + b2[1];
    }
}

extern "C" void kernel_launch(void* const* d_in, const int* in_sizes, int n_in,
                              void* d_out, int out_size, void* d_ws, size_t ws_size,
                              hipStream_t stream) {
    const float* x      = (const float*)d_in[0];
    const int*   ei     = (const int*)  d_in[1];
    const float* we_src = (const float*)d_in[2];
    const float* we_dst = (const float*)d_in[3];
    const float* be     = (const float*)d_in[4];
    const float* we2    = (const float*)d_in[5];
    const float* be2    = (const float*)d_in[6];
    const float* wc     = (const float*)d_in[7];
    const float* bc     = (const float*)d_in[8];
    const float* w1     = (const float*)d_in[9];
    const float* b1     = (const float*)d_in[10];
    const float* ln_g   = (const float*)d_in[11];
    const float* ln_b   = (const float*)d_in[12];
    const float* w2     = (const float*)d_in[13];
    const float* b2     = (const float*)d_in[14];

    const int N = in_sizes[0] / F;
    const int E = in_sizes[1] / 2;
    const int M16 = N / 16;
    const int K = (N + 15) >> 4;           // dst buckets (<= 4096 for N <= 65536)

    float* ws = (float*)d_ws;
    size_t off = 0;
    float* deg  = ws + off; off += (size_t)N;
    float* u    = ws + off; off += (size_t)N;
    float* gacc = ws + off; off += 128;
    int*   mmax = (int*)(ws + off); off += 1;
    float* S    = ws + off; off += 1;
    int*   hist = (int*)(ws + off); off += (size_t)K;
    const size_t zcount = off;             // all above zeroed together
    int*   cursor = (int*)(ws + off); off += (size_t)K;
    float* att  = ws + off; off += (size_t)N;
    float* c    = ws + off; off += (size_t)N;
    off = (off + 15) & ~(size_t)15;
    unsigned short* Wp = (unsigned short*)(ws + off); off += (12 * 8 * 64 * 8) / 2;
    off = (off + 15) & ~(size_t)15;
    _Float16* psh = (_Float16*)(ws + off); off += (size_t)N * ED / 2;
    _Float16* pdh = (_Float16*)(ws + off); off += (size_t)N * ED / 2;
    _Float16* hh  = (_Float16*)(ws + off); off += (size_t)N * H / 2;
    float* gate = ws + off; off += (size_t)E;
    off = (off + 1) & ~(size_t)1;          // 8-B align for int2
    int2* sd = (int2*)(ws + off); off += (size_t)E * 2;

    hipMemsetAsync(deg, 0, zcount * sizeof(float), stream);

    pack_kernel<<<(12 * 8 * 64 + 255) / 256, 256, 0, stream>>>(we_src, we_dst, wc, Wp);
    hist_kernel<<<(E + 255) / 256, 256, 0, stream>>>(ei, hist, E);
    scan_kernel<<<1, 1024, 0, stream>>>(hist, cursor, K);
    scatter_kernel<<<(E + 255) / 256, 256, 0, stream>>>(ei, cursor, sd, E);
    gemm_kernel<<<M16, 256, 0, stream>>>(x, Wp, bc, psh, pdh, hh, M16);
    edge_gate_kernel<<<(E + 63) / 64, 256, 0, stream>>>(sd, psh, pdh, be, we2, be2, gate, deg, E);
    stats_max_kernel<<<256, 256, 0, stream>>>(deg, mmax, N);
    stats_sum_kernel<<<256, 256, 0, stream>>>(deg, mmax, S, N);
    attc_kernel<<<(N + 255) / 256, 256, 0, stream>>>(deg, mmax, S, att, c, N);
    edge_u_kernel<<<(E + 255) / 256, 256, 0, stream>>>(sd, gate, c, u, E);
    pool_kernel<<<512, 128, 0, stream>>>(hh, att, u, gacc, N);
    cls_kernel<<<1, 64, 0, stream>>>(gacc, w1, b1, ln_g, ln_b, w2, b2, (float*)d_out);
}

// Round 6
// 368.568 us; speedup vs baseline: 1.5270x; 1.5270x over previous
//
#include <hip/hip_runtime.h>
#include <hip/hip_bf16.h>
#include <math.h>

constexpr int F  = 256;
constexpr int ED = 32;
constexpr int H  = 128;

typedef __attribute__((ext_vector_type(8))) short    short8v;
typedef __attribute__((ext_vector_type(4))) float    float4v;
typedef __attribute__((ext_vector_type(8))) _Float16 half8v;

static __device__ __forceinline__ unsigned short f2bf(float f) {
    unsigned int u = __float_as_uint(f);
    unsigned int r = (u + 0x7FFFu + ((u >> 16) & 1u)) >> 16;   // RNE
    return (unsigned short)r;
}

// bucket key: src-slice i (3b) x dst-slice j (3b), grouped 2x4 so that
// group q = (i>>1)*2 + (j>>2) owns buckets q*8 + (i&1)*4 + (j&3).
static __device__ __forceinline__ int edge_key(int s, int d, unsigned magic) {
    int i = __umulhi((unsigned)s, magic);   // ~ s*8/N, in [0,8)
    int j = __umulhi((unsigned)d, magic);
    int q = (i >> 1) * 2 + (j >> 2);
    return q * 8 + (i & 1) * 4 + (j & 3);
}

// ---------------- P0: pack weights into MFMA B-fragment order ----------------
__global__ __launch_bounds__(256) void pack_kernel(
    const float* __restrict__ we_src, const float* __restrict__ we_dst,
    const float* __restrict__ wc, unsigned short* __restrict__ Wp)
{
    int id = blockIdx.x * 256 + threadIdx.x;
    if (id >= 12 * 8 * 64) return;
    int lane = id & 63;
    int ks   = (id >> 6) & 7;
    int tile = id >> 9;
    int col  = tile * 16 + (lane & 15);
    int kb   = ks * 32 + (lane >> 4) * 8;

    short8v v;
    #pragma unroll
    for (int j = 0; j < 8; ++j) {
        int k = kb + j;
        float w;
        if (col < 32)       w = we_src[k * ED + col];
        else if (col < 64)  w = we_dst[k * ED + (col - 32)];
        else                w = wc[k * H + (col - 64)];
        v[j] = (short)f2bf(w);
    }
    *(short8v*)(Wp + (size_t)id * 8) = v;
}

// ---------------- P1: MFMA GEMM -> psh/pdh/hh (f16) ----------------
__global__ __launch_bounds__(256) void gemm_kernel(
    const float* __restrict__ x, const unsigned short* __restrict__ Wp,
    const float* __restrict__ bc,
    _Float16* __restrict__ psh, _Float16* __restrict__ pdh,
    _Float16* __restrict__ hh, int M16)
{
    __shared__ __align__(16) unsigned char As[16 * 512];

    const int t    = threadIdx.x;
    const int w    = t >> 6;
    const int lane = t & 63;

    const short8v* WpV = (const short8v*)Wp;
    short8v Bfr[3][8];
    #pragma unroll
    for (int ct = 0; ct < 3; ++ct)
        #pragma unroll
        for (int ks = 0; ks < 8; ++ks)
            Bfr[ct][ks] = WpV[(((w * 3 + ct) * 8 + ks) << 6) + lane];

    const int srow = t >> 4;
    const int sseg = t & 15;
    const int ssw  = (srow & 7) << 4;

    const int arow = lane & 15;
    const int asw  = (arow & 7) << 4;
    const int akb  = (lane >> 4) * 16;

    const int crow0 = (lane >> 4) * 4;
    const int ccol  = lane & 15;

    for (int rt = blockIdx.x; rt < M16; rt += gridDim.x) {
        const int n0 = rt * 16;
        {
            const float4* src = (const float4*)(x + (size_t)(n0 + srow) * F + sseg * 16);
            float4 f0 = src[0], f1 = src[1], f2 = src[2], f3 = src[3];
            short8v lo, hi;
            lo[0] = (short)f2bf(f0.x); lo[1] = (short)f2bf(f0.y);
            lo[2] = (short)f2bf(f0.z); lo[3] = (short)f2bf(f0.w);
            lo[4] = (short)f2bf(f1.x); lo[5] = (short)f2bf(f1.y);
            lo[6] = (short)f2bf(f1.z); lo[7] = (short)f2bf(f1.w);
            hi[0] = (short)f2bf(f2.x); hi[1] = (short)f2bf(f2.y);
            hi[2] = (short)f2bf(f2.z); hi[3] = (short)f2bf(f2.w);
            hi[4] = (short)f2bf(f3.x); hi[5] = (short)f2bf(f3.y);
            hi[6] = (short)f2bf(f3.z); hi[7] = (short)f2bf(f3.w);
            *(short8v*)&As[srow * 512 + ((sseg * 32 +  0) ^ ssw)] = lo;
            *(short8v*)&As[srow * 512 + ((sseg * 32 + 16) ^ ssw)] = hi;
        }
        __syncthreads();

        float4v accs[3];
        #pragma unroll
        for (int ct = 0; ct < 3; ++ct) accs[ct] = (float4v){0.f, 0.f, 0.f, 0.f};

        #pragma unroll
        for (int ks = 0; ks < 8; ++ks) {
            short8v a = *(const short8v*)&As[arow * 512 + ((ks * 64 + akb) ^ asw)];
            accs[0] = __builtin_amdgcn_mfma_f32_16x16x32_bf16(a, Bfr[0][ks], accs[0], 0, 0, 0);
            accs[1] = __builtin_amdgcn_mfma_f32_16x16x32_bf16(a, Bfr[1][ks], accs[1], 0, 0, 0);
            accs[2] = __builtin_amdgcn_mfma_f32_16x16x32_bf16(a, Bfr[2][ks], accs[2], 0, 0, 0);
        }

        #pragma unroll
        for (int ct = 0; ct < 3; ++ct) {
            const int gcol = w * 48 + ct * 16 + ccol;
            #pragma unroll
            for (int r = 0; r < 4; ++r) {
                const int row = n0 + crow0 + r;
                float v = accs[ct][r];
                if (gcol < 32) {
                    psh[(size_t)row * ED + gcol] = (_Float16)v;
                } else if (gcol < 64) {
                    pdh[(size_t)row * ED + (gcol - 32)] = (_Float16)v;
                } else {
                    float b = bc[gcol - 64];
                    hh[(size_t)row * H + (gcol - 64)] = (_Float16)fmaxf(v + b, 0.f);
                }
            }
        }
        __syncthreads();
    }
}

// ---------------- S1: 64-bucket histogram (LDS-aggregated) ----------------
__global__ __launch_bounds__(1024) void hist_kernel(
    const int* __restrict__ ei, int* __restrict__ hist, int E, unsigned magic)
{
    __shared__ int lh[64];
    const int t = threadIdx.x;
    if (t < 64) lh[t] = 0;
    __syncthreads();
    int e = blockIdx.x * 1024 + t;
    if (e < E) atomicAdd(&lh[edge_key(ei[e], ei[E + e], magic)], 1);
    __syncthreads();
    if (t < 64 && lh[t] > 0) atomicAdd(&hist[t], lh[t]);
}

// ---------------- S2: scan of 64 buckets (1 wave) ----------------
__global__ __launch_bounds__(64) void scan_kernel(
    const int* __restrict__ hist, int* __restrict__ cursor,
    int* __restrict__ bstart, int E)
{
    const int t = threadIdx.x;
    int v = hist[t];
    int inc = v;
    #pragma unroll
    for (int d = 1; d < 64; d <<= 1) {
        int n = __shfl_up(inc, d);
        if (t >= d) inc += n;
    }
    int excl = inc - v;
    cursor[t] = excl;
    bstart[t] = excl;
    if (t == 63) bstart[64] = E;
}

// ---------------- S3: scatter (block-aggregated cursor claims) ----------------
__global__ __launch_bounds__(1024) void scatter_kernel(
    const int* __restrict__ ei, int* __restrict__ cursor,
    int2* __restrict__ sd, int E, unsigned magic)
{
    __shared__ int lh[64];
    __shared__ int lbase[64];
    const int t = threadIdx.x;
    if (t < 64) lh[t] = 0;
    __syncthreads();
    const int e = blockIdx.x * 1024 + t;
    int s = 0, d = 0, key = 0, r = 0;
    const bool valid = (e < E);
    if (valid) {
        s = ei[e]; d = ei[E + e];
        key = edge_key(s, d, magic);
        r = atomicAdd(&lh[key], 1);
    }
    __syncthreads();
    if (t < 64 && lh[t] > 0) lbase[t] = atomicAdd(&cursor[t], lh[t]);
    __syncthreads();
    if (valid) sd[lbase[key] + r] = make_int2(s, d);
}

// ---------------- B: edge gate + deg (bucket-sorted, group-per-XCD) ----------
__global__ __launch_bounds__(256) void edge_gate_kernel(
    const int2* __restrict__ sd, const int* __restrict__ bstart,
    const _Float16* __restrict__ psh, const _Float16* __restrict__ pdh,
    const float* __restrict__ be, const float* __restrict__ we2,
    const float* __restrict__ be2,
    float* __restrict__ gate, float* __restrict__ deg)
{
    __shared__ float sbe[ED], swe2[ED];
    const int t = threadIdx.x;
    if (t < ED) { sbe[t] = be[t]; swe2[t] = we2[t]; }
    __syncthreads();

    const int q = blockIdx.x & 7;            // group -> XCD (round-robin dispatch)
    const int b = blockIdx.x >> 3;
    const int nb = gridDim.x >> 3;
    const int start = bstart[q * 8];
    const int end   = bstart[q * 8 + 8];
    const int seg = t & 3;

    for (int base = start + b * 64; base < end; base += nb * 64) {
        const int e = base + (t >> 2);
        if (e >= end) break;
        const int2 p = sd[e];

        half8v a = *(const half8v*)(psh + (size_t)p.x * ED + seg * 8);
        half8v bb = *(const half8v*)(pdh + (size_t)p.y * ED + seg * 8);
        float part = 0.f;
        #pragma unroll
        for (int j = 0; j < 8; ++j) {
            int k = seg * 8 + j;
            part += fmaxf((float)a[j] + (float)bb[j] + sbe[k], 0.f) * swe2[k];
        }
        part += __shfl_xor(part, 1);
        part += __shfl_xor(part, 2);

        if (seg == 0) {
            float logit = part + be2[0];
            float sg = 1.0f / (1.0f + expf(-logit));
            float gt = fminf(fmaxf(sg * 1.2f - 0.1f, 0.0f), 1.0f);
            gate[e] = gt;
            if (gt > 0.0f) atomicAdd(&deg[p.y], gt);
        }
    }
}

// ---------------- C1: grid-wide max(deg) ----------------
__global__ __launch_bounds__(256) void stats_max_kernel(
    const float* __restrict__ deg, int* __restrict__ mmax, int N)
{
    float m = 0.0f;   // deg >= 0
    for (int i = blockIdx.x * 256 + threadIdx.x; i < N; i += gridDim.x * 256)
        m = fmaxf(m, deg[i]);
    #pragma unroll
    for (int k = 1; k < 64; k <<= 1) m = fmaxf(m, __shfl_xor(m, k));
    if ((threadIdx.x & 63) == 0)
        atomicMax(mmax, __float_as_int(m));
}

// ---------------- C2: grid-wide sum exp(deg - mx) ----------------
__global__ __launch_bounds__(256) void stats_sum_kernel(
    const float* __restrict__ deg, const int* __restrict__ mmax,
    float* __restrict__ S, int N)
{
    const float mx = __int_as_float(*mmax);
    float sum = 0.0f;
    for (int i = blockIdx.x * 256 + threadIdx.x; i < N; i += gridDim.x * 256)
        sum += expf(deg[i] - mx);
    #pragma unroll
    for (int k = 1; k < 64; k <<= 1) sum += __shfl_xor(sum, k);
    if ((threadIdx.x & 63) == 0) atomicAdd(S, sum);
}

// ---------------- D: att + c elementwise ----------------
__global__ __launch_bounds__(256) void attc_kernel(
    const float* __restrict__ deg, const int* __restrict__ mmax,
    const float* __restrict__ S,
    float* __restrict__ att, float* __restrict__ c, int N)
{
    const int i = blockIdx.x * 256 + threadIdx.x;
    if (i >= N) return;
    const float mx = __int_as_float(*mmax);
    float a = expf(deg[i] - mx) / S[0];
    att[i] = a;
    c[i] = a / (deg[i] + 1e-6f);
}

// ---------------- E: u[src] += gate*c[dst] (sorted, group-per-XCD) ----------
__global__ __launch_bounds__(256) void edge_u_kernel(
    const int2* __restrict__ sd, const int* __restrict__ bstart,
    const float* __restrict__ gate, const float* __restrict__ c,
    float* __restrict__ u)
{
    const int q = blockIdx.x & 7;
    const int b = blockIdx.x >> 3;
    const int nb = gridDim.x >> 3;
    const int start = bstart[q * 8];
    const int end   = bstart[q * 8 + 8];

    for (int e = start + b * 256 + threadIdx.x; e < end; e += nb * 256) {
        float gt = gate[e];
        if (gt != 0.f) {
            int2 p = sd[e];
            atomicAdd(&u[p.x], gt * c[p.y]);
        }
    }
}

// ---------------- F: g = sum_i (att[i]+u[i]) * h[i,:] ----------------
__global__ __launch_bounds__(128) void pool_kernel(
    const _Float16* __restrict__ hh, const float* __restrict__ att,
    const float* __restrict__ u, float* __restrict__ gacc, int N)
{
    const int t = threadIdx.x;
    float acc = 0.f;
    for (int n = blockIdx.x; n < N; n += gridDim.x) {
        float wgt = att[n] + u[n];
        acc += wgt * (float)hh[(size_t)n * H + t];
    }
    atomicAdd(&gacc[t], acc);
}

// ---------------- G: classifier (1 wave) ----------------
__global__ __launch_bounds__(64) void cls_kernel(
    const float* __restrict__ gacc, const float* __restrict__ w1,
    const float* __restrict__ b1, const float* __restrict__ ln_g,
    const float* __restrict__ ln_b, const float* __restrict__ w2,
    const float* __restrict__ b2, float* __restrict__ out)
{
    __shared__ float gs[H];
    const int t = threadIdx.x;
    gs[t] = gacc[t];
    gs[t + 64] = gacc[t + 64];
    __syncthreads();

    float acc = b1[t];
    #pragma unroll 4
    for (int k = 0; k < H; ++k) acc += gs[k] * w1[k * 64 + t];
    float z = fmaxf(acc, 0.f);

    float sm = z;
    #pragma unroll
    for (int m = 1; m < 64; m <<= 1) sm += __shfl_xor(sm, m);
    float mn = sm * (1.0f / 64.0f);
    float dv = (z - mn) * (z - mn);
    float sv = dv;
    #pragma unroll
    for (int m = 1; m < 64; m <<= 1) sv += __shfl_xor(sv, m);
    float var = sv * (1.0f / 64.0f);

    float zn = (z - mn) * rsqrtf(var + 1e-5f) * ln_g[t] + ln_b[t];

    float w20 = w2[t * 2 + 0];
    float w21 = w2[t * 2 + 1];
    float ga = w20 * w20, gb = w20 * w21, gc = w21 * w21;
    float p0 = zn * w20, p1 = zn * w21;
    #pragma unroll
    for (int m = 1; m < 64; m <<= 1) {
        ga += __shfl_xor(ga, m);
        gb += __shfl_xor(gb, m);
        gc += __shfl_xor(gc, m);
        p0 += __shfl_xor(p0, m);
        p1 += __shfl_xor(p1, m);
    }
    if (t == 0) {
        float tr = ga + gc;
        float df = ga - gc;
        float eig = 0.5f * (tr + sqrtf(df * df + 4.0f * gb * gb));
        float sigma = sqrtf(eig);
        out[0] = p0 / sigma + b2[0];
        out[1] = p1 / sigma + b2[1];
    }
}

extern "C" void kernel_launch(void* const* d_in, const int* in_sizes, int n_in,
                              void* d_out, int out_size, void* d_ws, size_t ws_size,
                              hipStream_t stream) {
    const float* x      = (const float*)d_in[0];
    const int*   ei     = (const int*)  d_in[1];
    const float* we_src = (const float*)d_in[2];
    const float* we_dst = (const float*)d_in[3];
    const float* be     = (const float*)d_in[4];
    const float* we2    = (const float*)d_in[5];
    const float* be2    = (const float*)d_in[6];
    const float* wc     = (const float*)d_in[7];
    const float* bc     = (const float*)d_in[8];
    const float* w1     = (const float*)d_in[9];
    const float* b1     = (const float*)d_in[10];
    const float* ln_g   = (const float*)d_in[11];
    const float* ln_b   = (const float*)d_in[12];
    const float* w2     = (const float*)d_in[13];
    const float* b2     = (const float*)d_in[14];

    const int N = in_sizes[0] / F;
    const int E = in_sizes[1] / 2;
    const int M16 = N / 16;
    const unsigned magic = (unsigned)((8ULL << 32) / (unsigned long long)N);

    float* ws = (float*)d_ws;
    size_t off = 0;
    float* deg  = ws + off; off += (size_t)N;
    float* u    = ws + off; off += (size_t)N;
    float* gacc = ws + off; off += 128;
    int*   mmax = (int*)(ws + off); off += 1;
    float* S    = ws + off; off += 1;
    int*   hist = (int*)(ws + off); off += 64;
    const size_t zcount = off;             // all above zeroed together
    int*   cursor = (int*)(ws + off); off += 64;
    int*   bstart = (int*)(ws + off); off += 65;
    float* att  = ws + off; off += (size_t)N;
    float* c    = ws + off; off += (size_t)N;
    off = (off + 15) & ~(size_t)15;
    unsigned short* Wp = (unsigned short*)(ws + off); off += (12 * 8 * 64 * 8) / 2;
    off = (off + 15) & ~(size_t)15;
    _Float16* psh = (_Float16*)(ws + off); off += (size_t)N * ED / 2;
    _Float16* pdh = (_Float16*)(ws + off); off += (size_t)N * ED / 2;
    _Float16* hh  = (_Float16*)(ws + off); off += (size_t)N * H / 2;
    float* gate = ws + off; off += (size_t)E;
    off = (off + 1) & ~(size_t)1;          // 8-B align for int2
    int2* sd = (int2*)(ws + off); off += (size_t)E * 2;

    hipMemsetAsync(deg, 0, zcount * sizeof(float), stream);

    pack_kernel<<<(12 * 8 * 64 + 255) / 256, 256, 0, stream>>>(we_src, we_dst, wc, Wp);
    hist_kernel<<<(E + 1023) / 1024, 1024, 0, stream>>>(ei, hist, E, magic);
    scan_kernel<<<1, 64, 0, stream>>>(hist, cursor, bstart, E);
    scatter_kernel<<<(E + 1023) / 1024, 1024, 0, stream>>>(ei, cursor, sd, E, magic);
    gemm_kernel<<<1024, 256, 0, stream>>>(x, Wp, bc, psh, pdh, hh, M16);
    edge_gate_kernel<<<8 * 120, 256, 0, stream>>>(sd, bstart, psh, pdh, be, we2, be2, gate, deg);
    stats_max_kernel<<<256, 256, 0, stream>>>(deg, mmax, N);
    stats_sum_kernel<<<256, 256, 0, stream>>>(deg, mmax, S, N);
    attc_kernel<<<(N + 255) / 256, 256, 0, stream>>>(deg, mmax, S, att, c, N);
    edge_u_kernel<<<8 * 64, 256, 0, stream>>>(sd, bstart, gate, c, u);
    pool_kernel<<<512, 128, 0, stream>>>(hh, att, u, gacc, N);
    cls_kernel<<<1, 64, 0, stream>>>(gacc, w1, b1, ln_g, ln_b, w2, b2, (float*)d_out);
}

// Round 7
// 189.706 us; speedup vs baseline: 2.9667x; 1.9428x over previous
//
#include <hip/hip_runtime.h>
#include <hip/hip_bf16.h>
#include <math.h>

constexpr int F  = 256;
constexpr int ED = 32;
constexpr int H  = 128;
constexpr int NB = 64;            // 8 src-slices x 8 dst-slices
constexpr int SLICE_MAX = 6272;   // >= ceil(N/8) for N = 50000

typedef __attribute__((ext_vector_type(8))) short    short8v;
typedef __attribute__((ext_vector_type(4))) float    float4v;
typedef __attribute__((ext_vector_type(8))) _Float16 half8v;

static __device__ __forceinline__ unsigned short f2bf(float f) {
    unsigned int u = __float_as_uint(f);
    unsigned int r = (u + 0x7FFFu + ((u >> 16) & 1u)) >> 16;   // RNE
    return (unsigned short)r;
}

// ---------------- P0: pack weights into MFMA B-fragment order ----------------
__global__ __launch_bounds__(256) void pack_kernel(
    const float* __restrict__ we_src, const float* __restrict__ we_dst,
    const float* __restrict__ wc, unsigned short* __restrict__ Wp)
{
    int id = blockIdx.x * 256 + threadIdx.x;
    if (id >= 12 * 8 * 64) return;
    int lane = id & 63;
    int ks   = (id >> 6) & 7;
    int tile = id >> 9;
    int col  = tile * 16 + (lane & 15);
    int kb   = ks * 32 + (lane >> 4) * 8;

    short8v v;
    #pragma unroll
    for (int j = 0; j < 8; ++j) {
        int k = kb + j;
        float w;
        if (col < 32)       w = we_src[k * ED + col];
        else if (col < 64)  w = we_dst[k * ED + (col - 32)];
        else                w = wc[k * H + (col - 64)];
        v[j] = (short)f2bf(w);
    }
    *(short8v*)(Wp + (size_t)id * 8) = v;
}

// ---------------- P1: MFMA GEMM -> psh/pdh/hh (f16) ----------------
__global__ __launch_bounds__(256) void gemm_kernel(
    const float* __restrict__ x, const unsigned short* __restrict__ Wp,
    const float* __restrict__ bc,
    _Float16* __restrict__ psh, _Float16* __restrict__ pdh,
    _Float16* __restrict__ hh, int M16)
{
    __shared__ __align__(16) unsigned char As[16 * 512];

    const int t    = threadIdx.x;
    const int w    = t >> 6;
    const int lane = t & 63;

    const short8v* WpV = (const short8v*)Wp;
    short8v Bfr[3][8];
    #pragma unroll
    for (int ct = 0; ct < 3; ++ct)
        #pragma unroll
        for (int ks = 0; ks < 8; ++ks)
            Bfr[ct][ks] = WpV[(((w * 3 + ct) * 8 + ks) << 6) + lane];

    const int srow = t >> 4;
    const int sseg = t & 15;
    const int ssw  = (srow & 7) << 4;

    const int arow = lane & 15;
    const int asw  = (arow & 7) << 4;
    const int akb  = (lane >> 4) * 16;

    const int crow0 = (lane >> 4) * 4;
    const int ccol  = lane & 15;

    for (int rt = blockIdx.x; rt < M16; rt += gridDim.x) {
        const int n0 = rt * 16;
        {
            const float4* src = (const float4*)(x + (size_t)(n0 + srow) * F + sseg * 16);
            float4 f0 = src[0], f1 = src[1], f2 = src[2], f3 = src[3];
            short8v lo, hi;
            lo[0] = (short)f2bf(f0.x); lo[1] = (short)f2bf(f0.y);
            lo[2] = (short)f2bf(f0.z); lo[3] = (short)f2bf(f0.w);
            lo[4] = (short)f2bf(f1.x); lo[5] = (short)f2bf(f1.y);
            lo[6] = (short)f2bf(f1.z); lo[7] = (short)f2bf(f1.w);
            hi[0] = (short)f2bf(f2.x); hi[1] = (short)f2bf(f2.y);
            hi[2] = (short)f2bf(f2.z); hi[3] = (short)f2bf(f2.w);
            hi[4] = (short)f2bf(f3.x); hi[5] = (short)f2bf(f3.y);
            hi[6] = (short)f2bf(f3.z); hi[7] = (short)f2bf(f3.w);
            *(short8v*)&As[srow * 512 + ((sseg * 32 +  0) ^ ssw)] = lo;
            *(short8v*)&As[srow * 512 + ((sseg * 32 + 16) ^ ssw)] = hi;
        }
        __syncthreads();

        float4v accs[3];
        #pragma unroll
        for (int ct = 0; ct < 3; ++ct) accs[ct] = (float4v){0.f, 0.f, 0.f, 0.f};

        #pragma unroll
        for (int ks = 0; ks < 8; ++ks) {
            short8v a = *(const short8v*)&As[arow * 512 + ((ks * 64 + akb) ^ asw)];
            accs[0] = __builtin_amdgcn_mfma_f32_16x16x32_bf16(a, Bfr[0][ks], accs[0], 0, 0, 0);
            accs[1] = __builtin_amdgcn_mfma_f32_16x16x32_bf16(a, Bfr[1][ks], accs[1], 0, 0, 0);
            accs[2] = __builtin_amdgcn_mfma_f32_16x16x32_bf16(a, Bfr[2][ks], accs[2], 0, 0, 0);
        }

        #pragma unroll
        for (int ct = 0; ct < 3; ++ct) {
            const int gcol = w * 48 + ct * 16 + ccol;
            #pragma unroll
            for (int r = 0; r < 4; ++r) {
                const int row = n0 + crow0 + r;
                float v = accs[ct][r];
                if (gcol < 32) {
                    psh[(size_t)row * ED + gcol] = (_Float16)v;
                } else if (gcol < 64) {
                    pdh[(size_t)row * ED + (gcol - 32)] = (_Float16)v;
                } else {
                    float b = bc[gcol - 64];
                    hh[(size_t)row * H + (gcol - 64)] = (_Float16)fmaxf(v + b, 0.f);
                }
            }
        }
        __syncthreads();
    }
}

// ---------------- S1: 64-bucket histogram ----------------
__global__ __launch_bounds__(1024) void hist_kernel(
    const int* __restrict__ ei, int* __restrict__ hist, int E, int SL)
{
    __shared__ int lh[NB];
    const int t = threadIdx.x;
    if (t < NB) lh[t] = 0;
    __syncthreads();
    int e = blockIdx.x * 1024 + t;
    if (e < E) {
        unsigned i = (unsigned)ei[e] / (unsigned)SL;
        unsigned j = (unsigned)ei[E + e] / (unsigned)SL;
        atomicAdd(&lh[i * 8 + j], 1);
    }
    __syncthreads();
    if (t < NB && lh[t] > 0) atomicAdd(&hist[t], lh[t]);
}

// ---------------- S2: scan of 64 buckets (1 wave) ----------------
__global__ __launch_bounds__(64) void scan_kernel(
    const int* __restrict__ hist, int* __restrict__ cursor,
    int* __restrict__ bstart, int E)
{
    const int t = threadIdx.x;
    int v = hist[t];
    int inc = v;
    #pragma unroll
    for (int d = 1; d < 64; d <<= 1) {
        int n = __shfl_up(inc, d);
        if (t >= d) inc += n;
    }
    int excl = inc - v;
    cursor[t] = excl;
    bstart[t] = excl;
    if (t == 63) bstart[64] = E;
}

// ---------------- S3: scatter (block-aggregated cursor claims) ----------------
__global__ __launch_bounds__(1024) void scatter_kernel(
    const int* __restrict__ ei, int* __restrict__ cursor,
    int2* __restrict__ sd, int E, int SL)
{
    __shared__ int lh[NB];
    __shared__ int lbase[NB];
    const int t = threadIdx.x;
    if (t < NB) lh[t] = 0;
    __syncthreads();
    const int e = blockIdx.x * 1024 + t;
    int s = 0, d = 0, key = 0, r = 0;
    const bool valid = (e < E);
    if (valid) {
        s = ei[e]; d = ei[E + e];
        key = (int)((unsigned)s / (unsigned)SL) * 8 + (int)((unsigned)d / (unsigned)SL);
        r = atomicAdd(&lh[key], 1);
    }
    __syncthreads();
    if (t < NB && lh[t] > 0) lbase[t] = atomicAdd(&cursor[t], lh[t]);
    __syncthreads();
    if (valid) sd[lbase[key] + r] = make_int2(s, d);
}

// ---------------- B: edge gate; deg into LDS slice -> deg_part (no global atomics) --
// grid = 256: bid -> j = bid&7 (XCD), k = bid>>3, i = k>>2, p = k&3; bucket = i*8+j
__global__ __launch_bounds__(1024) void edge_gate_kernel(
    const int2* __restrict__ sd, const int* __restrict__ bstart,
    const _Float16* __restrict__ psh, const _Float16* __restrict__ pdh,
    const float* __restrict__ be, const float* __restrict__ we2,
    const float* __restrict__ be2,
    float* __restrict__ gate, float* __restrict__ deg_part, int N, int SL)
{
    __shared__ float sbe[ED], swe2[ED];
    __shared__ float sdeg[SLICE_MAX];
    const int t = threadIdx.x;
    if (t < ED) { sbe[t] = be[t]; swe2[t] = we2[t]; }
    for (int idx = t; idx < SLICE_MAX; idx += 1024) sdeg[idx] = 0.0f;
    __syncthreads();

    const int j = blockIdx.x & 7;
    const int k = blockIdx.x >> 3;
    const int i = k >> 2;
    const int p = k & 3;
    const int bucket = i * 8 + j;
    const int start = bstart[bucket];
    const int len   = bstart[bucket + 1] - start;
    const int cs = start + (len * p) / 4;
    const int ce = start + (len * (p + 1)) / 4;
    const int jbase = j * SL;
    const int jlen  = min(SL, N - jbase);
    const int seg = t & 3;

    for (int base = cs; base < ce; base += 256) {
        const int e = base + (t >> 2);
        if (e < ce) {
            const int2 pr = sd[e];
            half8v a  = *(const half8v*)(psh + (size_t)pr.x * ED + seg * 8);
            half8v bb = *(const half8v*)(pdh + (size_t)pr.y * ED + seg * 8);
            float part = 0.f;
            #pragma unroll
            for (int jj = 0; jj < 8; ++jj) {
                int kk = seg * 8 + jj;
                part += fmaxf((float)a[jj] + (float)bb[jj] + sbe[kk], 0.f) * swe2[kk];
            }
            part += __shfl_xor(part, 1);
            part += __shfl_xor(part, 2);
            if (seg == 0) {
                float logit = part + be2[0];
                float sg = 1.0f / (1.0f + expf(-logit));
                float gt = fminf(fmaxf(sg * 1.2f - 0.1f, 0.0f), 1.0f);
                gate[e] = gt;
                if (gt > 0.0f) atomicAdd(&sdeg[pr.y - jbase], gt);
            }
        }
    }
    __syncthreads();

    float* dst = deg_part + (size_t)(i * 4 + p) * N + jbase;
    for (int idx = t; idx < jlen; idx += 1024) dst[idx] = sdeg[idx];
}

// ---------------- R: out[n] = sum_{k<32} part[k*N+n] ----------------
__global__ __launch_bounds__(256) void reduce32_kernel(
    const float* __restrict__ part, float* __restrict__ out, int N)
{
    for (int n = blockIdx.x * 256 + threadIdx.x; n < N; n += gridDim.x * 256) {
        float s = 0.f;
        #pragma unroll
        for (int k = 0; k < 32; ++k) s += part[(size_t)k * N + n];
        out[n] = s;
    }
}

// ---------------- C1: grid-wide max(deg) ----------------
__global__ __launch_bounds__(256) void stats_max_kernel(
    const float* __restrict__ deg, int* __restrict__ mmax, int N)
{
    float m = 0.0f;   // deg >= 0
    for (int i = blockIdx.x * 256 + threadIdx.x; i < N; i += gridDim.x * 256)
        m = fmaxf(m, deg[i]);
    #pragma unroll
    for (int k = 1; k < 64; k <<= 1) m = fmaxf(m, __shfl_xor(m, k));
    if ((threadIdx.x & 63) == 0)
        atomicMax(mmax, __float_as_int(m));
}

// ---------------- C2: grid-wide sum exp(deg - mx) ----------------
__global__ __launch_bounds__(256) void stats_sum_kernel(
    const float* __restrict__ deg, const int* __restrict__ mmax,
    float* __restrict__ S, int N)
{
    const float mx = __int_as_float(*mmax);
    float sum = 0.0f;
    for (int i = blockIdx.x * 256 + threadIdx.x; i < N; i += gridDim.x * 256)
        sum += expf(deg[i] - mx);
    #pragma unroll
    for (int k = 1; k < 64; k <<= 1) sum += __shfl_xor(sum, k);
    if ((threadIdx.x & 63) == 0) atomicAdd(S, sum);
}

// ---------------- D: att + c elementwise ----------------
__global__ __launch_bounds__(256) void attc_kernel(
    const float* __restrict__ deg, const int* __restrict__ mmax,
    const float* __restrict__ S,
    float* __restrict__ att, float* __restrict__ c, int N)
{
    const int i = blockIdx.x * 256 + threadIdx.x;
    if (i >= N) return;
    const float mx = __int_as_float(*mmax);
    float a = expf(deg[i] - mx) / S[0];
    att[i] = a;
    c[i] = a / (deg[i] + 1e-6f);
}

// ---------------- E: u into LDS slice -> u_part (no global atomics) ----------
__global__ __launch_bounds__(1024) void edge_u_kernel(
    const int2* __restrict__ sd, const int* __restrict__ bstart,
    const float* __restrict__ gate, const float* __restrict__ c,
    float* __restrict__ u_part, int N, int SL)
{
    __shared__ float su[SLICE_MAX];
    const int t = threadIdx.x;
    for (int idx = t; idx < SLICE_MAX; idx += 1024) su[idx] = 0.0f;
    __syncthreads();

    const int j = blockIdx.x & 7;
    const int k = blockIdx.x >> 3;
    const int i = k >> 2;
    const int p = k & 3;
    const int bucket = i * 8 + j;
    const int start = bstart[bucket];
    const int len   = bstart[bucket + 1] - start;
    const int cs = start + (len * p) / 4;
    const int ce = start + (len * (p + 1)) / 4;
    const int ibase = i * SL;
    const int ilen  = min(SL, N - ibase);

    for (int e = cs + t; e < ce; e += 1024) {
        float gt = gate[e];
        if (gt != 0.f) {
            int2 pr = sd[e];
            atomicAdd(&su[pr.x - ibase], gt * c[pr.y]);
        }
    }
    __syncthreads();

    float* dst = u_part + (size_t)(j * 4 + p) * N + ibase;
    for (int idx = t; idx < ilen; idx += 1024) dst[idx] = su[idx];
}

// ---------------- F: g = sum_n (att[n]+u[n]) * h[n,:], vectorized ----------------
__global__ __launch_bounds__(256) void pool_kernel(
    const _Float16* __restrict__ hh, const float* __restrict__ att,
    const float* __restrict__ u, float* __restrict__ gacc, int N)
{
    __shared__ float red[16][128];
    const int t = threadIdx.x;
    const int lane = t & 15;     // 16 lanes x 8 cols = 128 cols
    const int row  = t >> 4;     // 16 rows per iter

    float acc[8];
    #pragma unroll
    for (int q = 0; q < 8; ++q) acc[q] = 0.f;

    for (int n = blockIdx.x * 16 + row; n < N; n += gridDim.x * 16) {
        float wgt = att[n] + u[n];
        half8v hv = *(const half8v*)(hh + (size_t)n * H + lane * 8);
        #pragma unroll
        for (int q = 0; q < 8; ++q) acc[q] += wgt * (float)hv[q];
    }
    #pragma unroll
    for (int q = 0; q < 8; ++q) red[row][lane * 8 + q] = acc[q];
    __syncthreads();
    if (t < 128) {
        float s = 0.f;
        #pragma unroll
        for (int r = 0; r < 16; ++r) s += red[r][t];
        atomicAdd(&gacc[t], s);
    }
}

// ---------------- G: classifier (1 wave) ----------------
__global__ __launch_bounds__(64) void cls_kernel(
    const float* __restrict__ gacc, const float* __restrict__ w1,
    const float* __restrict__ b1, const float* __restrict__ ln_g,
    const float* __restrict__ ln_b, const float* __restrict__ w2,
    const float* __restrict__ b2, float* __restrict__ out)
{
    __shared__ float gs[H];
    const int t = threadIdx.x;
    gs[t] = gacc[t];
    gs[t + 64] = gacc[t + 64];
    __syncthreads();

    float acc = b1[t];
    #pragma unroll 4
    for (int k = 0; k < H; ++k) acc += gs[k] * w1[k * 64 + t];
    float z = fmaxf(acc, 0.f);

    float sm = z;
    #pragma unroll
    for (int m = 1; m < 64; m <<= 1) sm += __shfl_xor(sm, m);
    float mn = sm * (1.0f / 64.0f);
    float dv = (z - mn) * (z - mn);
    float sv = dv;
    #pragma unroll
    for (int m = 1; m < 64; m <<= 1) sv += __shfl_xor(sv, m);
    float var = sv * (1.0f / 64.0f);

    float zn = (z - mn) * rsqrtf(var + 1e-5f) * ln_g[t] + ln_b[t];

    float w20 = w2[t * 2 + 0];
    float w21 = w2[t * 2 + 1];
    float ga = w20 * w20, gb = w20 * w21, gc = w21 * w21;
    float p0 = zn * w20, p1 = zn * w21;
    #pragma unroll
    for (int m = 1; m < 64; m <<= 1) {
        ga += __shfl_xor(ga, m);
        gb += __shfl_xor(gb, m);
        gc += __shfl_xor(gc, m);
        p0 += __shfl_xor(p0, m);
        p1 += __shfl_xor(p1, m);
    }
    if (t == 0) {
        float tr = ga + gc;
        float df = ga - gc;
        float eig = 0.5f * (tr + sqrtf(df * df + 4.0f * gb * gb));
        float sigma = sqrtf(eig);
        out[0] = p0 / sigma + b2[0];
        out[1] = p1 / sigma + b2[1];
    }
}

extern "C" void kernel_launch(void* const* d_in, const int* in_sizes, int n_in,
                              void* d_out, int out_size, void* d_ws, size_t ws_size,
                              hipStream_t stream) {
    const float* x      = (const float*)d_in[0];
    const int*   ei     = (const int*)  d_in[1];
    const float* we_src = (const float*)d_in[2];
    const float* we_dst = (const float*)d_in[3];
    const float* be     = (const float*)d_in[4];
    const float* we2    = (const float*)d_in[5];
    const float* be2    = (const float*)d_in[6];
    const float* wc     = (const float*)d_in[7];
    const float* bc     = (const float*)d_in[8];
    const float* w1     = (const float*)d_in[9];
    const float* b1     = (const float*)d_in[10];
    const float* ln_g   = (const float*)d_in[11];
    const float* ln_b   = (const float*)d_in[12];
    const float* w2     = (const float*)d_in[13];
    const float* b2     = (const float*)d_in[14];

    const int N = in_sizes[0] / F;
    const int E = in_sizes[1] / 2;
    const int M16 = N / 16;
    const int SL = (N + 7) / 8;            // slice length (6250 for N=50000)

    float* ws = (float*)d_ws;
    size_t off = 0;
    float* deg  = ws + off; off += (size_t)N;
    float* u    = ws + off; off += (size_t)N;
    float* gacc = ws + off; off += 128;
    int*   mmax = (int*)(ws + off); off += 1;
    float* S    = ws + off; off += 1;
    int*   hist = (int*)(ws + off); off += NB;
    const size_t zcount = off;             // gacc/mmax/S/hist (+deg/u harmless)
    int*   cursor = (int*)(ws + off); off += NB;
    int*   bstart = (int*)(ws + off); off += NB + 1;
    float* att  = ws + off; off += (size_t)N;
    float* c    = ws + off; off += (size_t)N;
    off = (off + 15) & ~(size_t)15;
    unsigned short* Wp = (unsigned short*)(ws + off); off += (12 * 8 * 64 * 8) / 2;
    off = (off + 15) & ~(size_t)15;
    _Float16* psh = (_Float16*)(ws + off); off += (size_t)N * ED / 2;
    _Float16* pdh = (_Float16*)(ws + off); off += (size_t)N * ED / 2;
    _Float16* hh  = (_Float16*)(ws + off); off += (size_t)N * H / 2;
    float* gate = ws + off; off += (size_t)E;
    off = (off + 1) & ~(size_t)1;          // 8-B align for int2
    int2* sd = (int2*)(ws + off); off += (size_t)E * 2;
    float* deg_part = ws + off; off += (size_t)32 * N;
    float* u_part   = ws + off; off += (size_t)32 * N;

    hipMemsetAsync(deg, 0, zcount * sizeof(float), stream);

    pack_kernel<<<(12 * 8 * 64 + 255) / 256, 256, 0, stream>>>(we_src, we_dst, wc, Wp);
    hist_kernel<<<(E + 1023) / 1024, 1024, 0, stream>>>(ei, hist, E, SL);
    scan_kernel<<<1, 64, 0, stream>>>(hist, cursor, bstart, E);
    scatter_kernel<<<(E + 1023) / 1024, 1024, 0, stream>>>(ei, cursor, sd, E, SL);
    gemm_kernel<<<1024, 256, 0, stream>>>(x, Wp, bc, psh, pdh, hh, M16);
    edge_gate_kernel<<<256, 1024, 0, stream>>>(sd, bstart, psh, pdh, be, we2, be2,
                                               gate, deg_part, N, SL);
    reduce32_kernel<<<256, 256, 0, stream>>>(deg_part, deg, N);
    stats_max_kernel<<<256, 256, 0, stream>>>(deg, mmax, N);
    stats_sum_kernel<<<256, 256, 0, stream>>>(deg, mmax, S, N);
    attc_kernel<<<(N + 255) / 256, 256, 0, stream>>>(deg, mmax, S, att, c, N);
    edge_u_kernel<<<256, 1024, 0, stream>>>(sd, bstart, gate, c, u_part, N, SL);
    reduce32_kernel<<<256, 256, 0, stream>>>(u_part, u, N);
    pool_kernel<<<256, 256, 0, stream>>>(hh, att, u, gacc, N);
    cls_kernel<<<1, 64, 0, stream>>>(gacc, w1, b1, ln_g, ln_b, w2, b2, (float*)d_out);
}